// Round 1
// baseline (6811.979 us; speedup 1.0000x reference)
//
#include <hip/hip_runtime.h>

#define TLEN 2048
#define BATCH 32
#define DIN 64
#define HID 128

typedef _Float16 h2 __attribute__((ext_vector_type(2)));
typedef float f4 __attribute__((ext_vector_type(4)));

#if defined(__has_builtin)
#if __has_builtin(__builtin_amdgcn_fdot2)
#define FDOT2(a, b, c) __builtin_amdgcn_fdot2((a), (b), (c), false)
#endif
#endif
#ifndef FDOT2
#define FDOT2(a, b, c) ((c) + (float)(a).x * (float)(b).x + (float)(a).y * (float)(b).y)
#endif

__device__ __forceinline__ float sigm(float x) {
    return 1.0f / (1.0f + __expf(-x));
}
__device__ __forceinline__ float tanh_c(float x) {
    x = fminf(fmaxf(x, -15.0f), 15.0f);
    float e = __expf(2.0f * x);
    return (e - 1.0f) / (e + 1.0f);
}

__global__ __launch_bounds__(512, 2) void lstm2_persist(
    const float* __restrict__ X,
    const float* __restrict__ Wih0, const float* __restrict__ Whh0,
    const float* __restrict__ bih0, const float* __restrict__ bhh0,
    const float* __restrict__ Wih1, const float* __restrict__ Whh1,
    const float* __restrict__ bih1, const float* __restrict__ bhh1,
    float* __restrict__ Out)
{
    // Wih0 packed f16 pairs, row stride 33 dwords (bank-conflict break: 2-way max)
    __shared__ unsigned int wih0_lds[512 * 33];
    __shared__ _Float16 h0buf[2][HID];   // double-buffered hidden states (packed-pair readable)
    __shared__ _Float16 h1buf[2][HID];

    const int b  = blockIdx.x;
    const int t  = threadIdx.x;
    const int rg = t >> 2;   // hidden unit owned by this quad
    const int kg = t & 3;    // k-slice within quad

    // ---- one-time staging: Wih0 -> LDS as f16 pairs ----
    {
        const float2* src = (const float2*)(Wih0 + t * DIN);
        #pragma unroll
        for (int i = 0; i < 32; ++i) {
            float2 v = src[i];
            h2 p; p.x = (_Float16)v.x; p.y = (_Float16)v.y;
            wih0_lds[t * 33 + i] = __builtin_bit_cast(unsigned int, p);
        }
    }
    if (t < HID) {
        h0buf[0][t] = (_Float16)0.0f; h0buf[1][t] = (_Float16)0.0f;
        h1buf[0][t] = (_Float16)0.0f; h1buf[1][t] = (_Float16)0.0f;
    }

    // ---- one-time: recurrent weights -> registers (f16 pairs) ----
    // rows: m=0 -> i-gate (rg), m=1 -> f (rg+128), m=2 -> g (rg+256), m=3 -> o (rg+384)
    h2 whh0[4][16], wih1[4][16], whh1[4][16];
    float bi0[4], bi1[4];
    #pragma unroll
    for (int m = 0; m < 4; ++m) {
        const int row = rg + 128 * m;
        const float2* a = (const float2*)(Whh0 + row * HID + kg * 32);
        const float2* c = (const float2*)(Wih1 + row * HID + kg * 32);
        const float2* d = (const float2*)(Whh1 + row * HID + kg * 32);
        #pragma unroll
        for (int i = 0; i < 16; ++i) {
            float2 v; h2 w;
            v = a[i]; w.x = (_Float16)v.x; w.y = (_Float16)v.y; whh0[m][i] = w;
            v = c[i]; w.x = (_Float16)v.x; w.y = (_Float16)v.y; wih1[m][i] = w;
            v = d[i]; w.x = (_Float16)v.x; w.y = (_Float16)v.y; whh1[m][i] = w;
        }
        // bias only on kg==0 lane so the quad-reduce counts it once
        bi0[m] = (kg == 0) ? (bih0[row] + bhh0[row]) : 0.0f;
        bi1[m] = (kg == 0) ? (bih1[row] + bhh1[row]) : 0.0f;
    }

    float c0 = 0.0f, c1 = 0.0f;
    __syncthreads();

    // ---- x prefetch (one step ahead), 16 floats per thread (slice kg) ----
    f4 xA[4], xB[4];
    {
        const f4* xp = (const f4*)(X + ((size_t)b * TLEN) * DIN + kg * 16);
        #pragma unroll
        for (int j = 0; j < 4; ++j) xA[j] = xp[j];
    }

    auto step = [&](int tt, f4 (&xc)[4], f4 (&xn)[4]) {
        const int cur = tt & 1, nxt = cur ^ 1;

        // convert current x slice to 8 f16 pairs
        h2 xh[8];
        const float* xf = (const float*)xc;
        #pragma unroll
        for (int j = 0; j < 8; ++j) {
            h2 p; p.x = (_Float16)xf[2 * j]; p.y = (_Float16)xf[2 * j + 1];
            xh[j] = p;
        }
        // issue prefetch of next step's x (consumed next step; waitcnt lands there)
        {
            const int tn = (tt + 1 < TLEN) ? tt + 1 : TLEN - 1;
            const f4* xp = (const f4*)(X + ((size_t)b * TLEN + tn) * DIN + kg * 16);
            #pragma unroll
            for (int j = 0; j < 4; ++j) xn[j] = xp[j];
        }

        // ---------- layer 0 gates ----------
        float p0[4];
        #pragma unroll
        for (int m = 0; m < 4; ++m) p0[m] = bi0[m];

        // x contribution (weights streamed from LDS)
        #pragma unroll
        for (int m = 0; m < 4; ++m) {
            const unsigned int* wr = &wih0_lds[(rg + 128 * m) * 33 + kg * 8];
            #pragma unroll
            for (int i = 0; i < 8; ++i) {
                h2 w = __builtin_bit_cast(h2, wr[i]);
                p0[m] = FDOT2(w, xh[i], p0[m]);
            }
        }
        // recurrent h0 contribution (register weights, LDS h broadcast)
        {
            const unsigned int* hr = (const unsigned int*)&h0buf[cur][0];
            #pragma unroll
            for (int i = 0; i < 16; ++i) {
                h2 hv = __builtin_bit_cast(h2, hr[kg * 16 + i]);
                #pragma unroll
                for (int m = 0; m < 4; ++m)
                    p0[m] = FDOT2(whh0[m][i], hv, p0[m]);
            }
        }
        // quad butterfly: every lane gets full i,f,g,o preacts of unit rg
        #pragma unroll
        for (int m = 0; m < 4; ++m) {
            p0[m] += __shfl_xor(p0[m], 1, 4);
            p0[m] += __shfl_xor(p0[m], 2, 4);
        }
        {
            float ii = sigm(p0[0]), ff = sigm(p0[1]);
            float gg = tanh_c(p0[2]), oo = sigm(p0[3]);
            c0 = ff * c0 + ii * gg;
            float h0v = oo * tanh_c(c0);
            if (kg == 0) h0buf[nxt][rg] = (_Float16)h0v;
        }
        __syncthreads();   // h0(t) visible for layer 1

        // ---------- layer 1 gates ----------
        float q[4];
        #pragma unroll
        for (int m = 0; m < 4; ++m) q[m] = bi1[m];
        {
            const unsigned int* hr = (const unsigned int*)&h0buf[nxt][0];
            #pragma unroll
            for (int i = 0; i < 16; ++i) {
                h2 hv = __builtin_bit_cast(h2, hr[kg * 16 + i]);
                #pragma unroll
                for (int m = 0; m < 4; ++m)
                    q[m] = FDOT2(wih1[m][i], hv, q[m]);
            }
        }
        {
            const unsigned int* hr = (const unsigned int*)&h1buf[cur][0];
            #pragma unroll
            for (int i = 0; i < 16; ++i) {
                h2 hv = __builtin_bit_cast(h2, hr[kg * 16 + i]);
                #pragma unroll
                for (int m = 0; m < 4; ++m)
                    q[m] = FDOT2(whh1[m][i], hv, q[m]);
            }
        }
        #pragma unroll
        for (int m = 0; m < 4; ++m) {
            q[m] += __shfl_xor(q[m], 1, 4);
            q[m] += __shfl_xor(q[m], 2, 4);
        }
        {
            float ii = sigm(q[0]), ff = sigm(q[1]);
            float gg = tanh_c(q[2]), oo = sigm(q[3]);
            c1 = ff * c1 + ii * gg;
            float h1v = oo * tanh_c(c1);
            if (kg == 0) {
                h1buf[nxt][rg] = (_Float16)h1v;
                Out[((size_t)b * TLEN + tt) * HID + rg] = h1v;
            }
        }
        __syncthreads();   // h1(t) visible before next step's reads
    };

    for (int tt = 0; tt < TLEN; tt += 2) {
        step(tt, xA, xB);
        step(tt + 1, xB, xA);
    }
}

extern "C" void kernel_launch(void* const* d_in, const int* in_sizes, int n_in,
                              void* d_out, int out_size, void* d_ws, size_t ws_size,
                              hipStream_t stream) {
    const float* X    = (const float*)d_in[0];
    const float* Wih0 = (const float*)d_in[1];
    const float* Whh0 = (const float*)d_in[2];
    const float* bih0 = (const float*)d_in[3];
    const float* bhh0 = (const float*)d_in[4];
    const float* Wih1 = (const float*)d_in[5];
    const float* Whh1 = (const float*)d_in[6];
    const float* bih1 = (const float*)d_in[7];
    const float* bhh1 = (const float*)d_in[8];
    float* Out = (float*)d_out;

    hipLaunchKernelGGL(lstm2_persist, dim3(BATCH), dim3(512), 0, stream,
                       X, Wih0, Whh0, bih0, bhh0, Wih1, Whh1, bih1, bhh1, Out);
}

// Round 3
// 3862.029 us; speedup vs baseline: 1.7638x; 1.7638x over previous
//
#include <hip/hip_runtime.h>

#define TLEN 2048
#define BATCH 32
#define DIN 64
#define HID 128

typedef _Float16 h2 __attribute__((ext_vector_type(2)));
typedef float f4 __attribute__((ext_vector_type(4)));

#if defined(__has_builtin)
#if __has_builtin(__builtin_amdgcn_fdot2)
#define FDOT2(a, b, c) __builtin_amdgcn_fdot2((a), (b), (c), false)
#endif
#endif
#ifndef FDOT2
#define FDOT2(a, b, c) ((c) + (float)(a).x * (float)(b).x + (float)(a).y * (float)(b).y)
#endif

__device__ __forceinline__ float sigm(float x) { return 1.0f / (1.0f + __expf(-x)); }
__device__ __forceinline__ float tanh_c(float x) {
    x = fminf(fmaxf(x, -15.0f), 15.0f);
    float e = __expf(2.0f * x);
    return (e - 1.0f) / (e + 1.0f);
}

// quad butterfly: after this, all 4 lanes of the quad hold the full sums
// (R1-proven __shfl_xor form; DPP was the prime suspect in R2's failure)
__device__ __forceinline__ void qreduce(float (&v)[4]) {
    #pragma unroll
    for (int m = 0; m < 4; ++m) {
        v[m] += __shfl_xor(v[m], 1, 4);
        v[m] += __shfl_xor(v[m], 2, 4);
    }
}

// ============================================================================
// Kernel 1: XG[b,t,j] = Wih0[row_j]·x[b,t] + bih0[row_j] + bhh0[row_j],
// row_j = (j>>2) + 128*(j&3)  (unit j>>2, gate j&3) -> coalesced stores,
// layout matches the persistent kernel's thread mapping exactly.
// ============================================================================
template <typename XT>
__global__ __launch_bounds__(512) void xg_precompute(
    const float* __restrict__ X, const float* __restrict__ Wih0,
    const float* __restrict__ bih0, const float* __restrict__ bhh0,
    XT* __restrict__ XG)
{
    __shared__ float xs[16][DIN];
    const int blk = blockIdx.x;               // over B * (T/16)
    const int b   = blk / (TLEN / 16);
    const int tc  = blk % (TLEN / 16);
    const int j   = threadIdx.x;
    const int row = (j >> 2) + 128 * (j & 3);

    const float* xsrc = X + ((size_t)b * TLEN + (size_t)tc * 16) * DIN;
    for (int i = j; i < 16 * DIN; i += 512) ((float*)xs)[i] = xsrc[i];
    __syncthreads();

    f4 w[16];
    const f4* wp = (const f4*)(Wih0 + (size_t)row * DIN);
    #pragma unroll
    for (int i = 0; i < 16; ++i) w[i] = wp[i];
    const float bias = bih0[row] + bhh0[row];

    XT* dst = XG + ((size_t)b * TLEN + (size_t)tc * 16) * 512 + j;
    #pragma unroll 4
    for (int t = 0; t < 16; ++t) {
        float acc = bias;
        const f4* xv = (const f4*)&xs[t][0];
        #pragma unroll
        for (int i = 0; i < 16; ++i) {
            f4 x4 = xv[i];
            acc += w[i][0] * x4[0] + w[i][1] * x4[1] + w[i][2] * x4[2] + w[i][3] * x4[3];
        }
        dst[(size_t)t * 512] = (XT)acc;
    }
}

// ============================================================================
// Kernel 2: persistent fused 2-layer LSTM, one block per batch element.
// Thread t0: unit rg = t0>>2, k-slice kg = t0&3.
// Iter tt: layer0 -> h0(tt+1) from xg(tt+1), h0(tt);
//          layer1 -> h1(tt)   from h0(tt),  h1(tt-1).   ONE barrier/step.
// All recurrent weights register-resident as f16 pairs (192 VGPRs).
// ============================================================================
template <typename XT>
__global__ __launch_bounds__(512, 2) void lstm2_fused(
    const XT* __restrict__ XG,
    const float* __restrict__ Whh0,
    const float* __restrict__ Wih1, const float* __restrict__ Whh1,
    const float* __restrict__ bih1, const float* __restrict__ bhh1,
    float* __restrict__ Out)
{
    __shared__ alignas(16) _Float16 h0buf[2][HID];
    __shared__ alignas(16) _Float16 h1buf[2][HID];

    const int b  = blockIdx.x;
    const int t0 = threadIdx.x;
    const int rg = t0 >> 2;
    const int kg = t0 & 3;

    // weights -> registers (f16 pairs)
    h2 whh0[4][16], wih1[4][16], whh1[4][16];
    #pragma unroll
    for (int m = 0; m < 4; ++m) {
        const int row = rg + 128 * m;
        const float2* a = (const float2*)(Whh0 + (size_t)row * HID + kg * 32);
        const float2* c = (const float2*)(Wih1 + (size_t)row * HID + kg * 32);
        const float2* d = (const float2*)(Whh1 + (size_t)row * HID + kg * 32);
        #pragma unroll
        for (int i = 0; i < 16; ++i) {
            float2 v; h2 w;
            v = a[i]; w.x = (_Float16)v.x; w.y = (_Float16)v.y; whh0[m][i] = w;
            v = c[i]; w.x = (_Float16)v.x; w.y = (_Float16)v.y; wih1[m][i] = w;
            v = d[i]; w.x = (_Float16)v.x; w.y = (_Float16)v.y; whh1[m][i] = w;
        }
    }

    // lane-gate selection mask + pre-masked layer-1 bias:
    // lane kg injects its slice's value into component m==kg; quad-reduce sums once.
    float msel[4], bi1m[4];
    {
        const int rowk = rg + 128 * kg;
        const float B1 = bih1[rowk] + bhh1[rowk];
        #pragma unroll
        for (int m = 0; m < 4; ++m) {
            msel[m] = (kg == m) ? 1.0f : 0.0f;
            bi1m[m] = msel[m] * B1;
        }
    }

    if (t0 < HID) {
        h0buf[0][t0] = (_Float16)0.0f; h0buf[1][t0] = (_Float16)0.0f;
        h1buf[0][t0] = (_Float16)0.0f; h1buf[1][t0] = (_Float16)0.0f;
    }
    __syncthreads();

    const XT* xgp = XG + ((size_t)b * TLEN) * 512 + t0;
    float c0 = 0.0f, c1 = 0.0f;

    // prologue: h0(0) from xg(0), h0(-1)=0
    {
        float xg0 = (float)xgp[0];
        float p[4];
        #pragma unroll
        for (int m = 0; m < 4; ++m) p[m] = msel[m] * xg0;
        qreduce(p);
        float ii = sigm(p[0]), gg = tanh_c(p[2]), oo = sigm(p[3]);
        c0 = ii * gg;
        if (kg == 0) h0buf[0][rg] = (_Float16)(oo * tanh_c(c0));
    }
    __syncthreads();

    // xg prefetch ring (depth 2)
    float xg_next = (float)xgp[512];          // xg(1), used at iter 0
    XT    xg_pend = xgp[2 * 512];             // xg(2), used at iter 1

    for (int tt = 0; tt < TLEN; ++tt) {
        const int cur = tt & 1, nxt = cur ^ 1;

        const float xgn = xg_next;            // xg(tt+1)
        xg_next = (float)xg_pend;
        {
            const int tnn = (tt + 3 < TLEN) ? tt + 3 : TLEN - 1;
            xg_pend = xgp[(size_t)tnn * 512];
        }

        float p[4], q[4];
        #pragma unroll
        for (int m = 0; m < 4; ++m) { p[m] = msel[m] * xgn; q[m] = bi1m[m]; }

        // h0(tt) slice feeds BOTH whh0 (layer0) and wih1 (layer1) dots;
        // h1(tt-1) slice feeds whh1.  ds_read_b64 per pair of f16-pairs.
        const uint2* H0 = (const uint2*)&h0buf[cur][0];
        const uint2* H1 = (const uint2*)&h1buf[cur][0];
        #pragma unroll
        for (int i8 = 0; i8 < 8; ++i8) {
            const uint2 ha = H0[kg * 8 + i8];
            const uint2 hb = H1[kg * 8 + i8];
            const h2 hv0 = __builtin_bit_cast(h2, ha.x);
            const h2 hv1 = __builtin_bit_cast(h2, ha.y);
            const h2 gv0 = __builtin_bit_cast(h2, hb.x);
            const h2 gv1 = __builtin_bit_cast(h2, hb.y);
            #pragma unroll
            for (int m = 0; m < 4; ++m) {
                p[m] = FDOT2(whh0[m][2 * i8],     hv0, p[m]);
                p[m] = FDOT2(whh0[m][2 * i8 + 1], hv1, p[m]);
                q[m] = FDOT2(wih1[m][2 * i8],     hv0, q[m]);
                q[m] = FDOT2(wih1[m][2 * i8 + 1], hv1, q[m]);
                q[m] = FDOT2(whh1[m][2 * i8],     gv0, q[m]);
                q[m] = FDOT2(whh1[m][2 * i8 + 1], gv1, q[m]);
            }
        }

        qreduce(p);
        qreduce(q);

        // layer0 -> h0(tt+1)
        {
            float ii = sigm(p[0]), ff = sigm(p[1]);
            float gg = tanh_c(p[2]), oo = sigm(p[3]);
            c0 = ff * c0 + ii * gg;
            if (kg == 0) h0buf[nxt][rg] = (_Float16)(oo * tanh_c(c0));
        }
        // layer1 -> h1(tt)
        {
            float ii = sigm(q[0]), ff = sigm(q[1]);
            float gg = tanh_c(q[2]), oo = sigm(q[3]);
            c1 = ff * c1 + ii * gg;
            float h1v = oo * tanh_c(c1);
            if (kg == 0) {
                h1buf[nxt][rg] = (_Float16)h1v;
                Out[((size_t)b * TLEN + tt) * HID + rg] = h1v;
            }
        }
        __syncthreads();
    }
}

// ============================================================================
// Fallback (ws too small): round-1 kernel, known-correct at 6.8 ms.
// ============================================================================
__global__ __launch_bounds__(512, 2) void lstm2_persist(
    const float* __restrict__ X,
    const float* __restrict__ Wih0, const float* __restrict__ Whh0,
    const float* __restrict__ bih0, const float* __restrict__ bhh0,
    const float* __restrict__ Wih1, const float* __restrict__ Whh1,
    const float* __restrict__ bih1, const float* __restrict__ bhh1,
    float* __restrict__ Out)
{
    __shared__ unsigned int wih0_lds[512 * 33];
    __shared__ _Float16 h0buf[2][HID];
    __shared__ _Float16 h1buf[2][HID];

    const int b  = blockIdx.x;
    const int t  = threadIdx.x;
    const int rg = t >> 2;
    const int kg = t & 3;

    {
        const float2* src = (const float2*)(Wih0 + t * DIN);
        #pragma unroll
        for (int i = 0; i < 32; ++i) {
            float2 v = src[i];
            h2 p; p.x = (_Float16)v.x; p.y = (_Float16)v.y;
            wih0_lds[t * 33 + i] = __builtin_bit_cast(unsigned int, p);
        }
    }
    if (t < HID) {
        h0buf[0][t] = (_Float16)0.0f; h0buf[1][t] = (_Float16)0.0f;
        h1buf[0][t] = (_Float16)0.0f; h1buf[1][t] = (_Float16)0.0f;
    }

    h2 whh0[4][16], wih1[4][16], whh1[4][16];
    float bi0[4], bi1[4];
    #pragma unroll
    for (int m = 0; m < 4; ++m) {
        const int row = rg + 128 * m;
        const float2* a = (const float2*)(Whh0 + row * HID + kg * 32);
        const float2* c = (const float2*)(Wih1 + row * HID + kg * 32);
        const float2* d = (const float2*)(Whh1 + row * HID + kg * 32);
        #pragma unroll
        for (int i = 0; i < 16; ++i) {
            float2 v; h2 w;
            v = a[i]; w.x = (_Float16)v.x; w.y = (_Float16)v.y; whh0[m][i] = w;
            v = c[i]; w.x = (_Float16)v.x; w.y = (_Float16)v.y; wih1[m][i] = w;
            v = d[i]; w.x = (_Float16)v.x; w.y = (_Float16)v.y; whh1[m][i] = w;
        }
        bi0[m] = (kg == 0) ? (bih0[row] + bhh0[row]) : 0.0f;
        bi1[m] = (kg == 0) ? (bih1[row] + bhh1[row]) : 0.0f;
    }

    float c0 = 0.0f, c1 = 0.0f;
    __syncthreads();

    f4 xA[4], xB[4];
    {
        const f4* xp = (const f4*)(X + ((size_t)b * TLEN) * DIN + kg * 16);
        #pragma unroll
        for (int j = 0; j < 4; ++j) xA[j] = xp[j];
    }

    auto step = [&](int tt, f4 (&xc)[4], f4 (&xn)[4]) {
        const int cur = tt & 1, nxt = cur ^ 1;
        h2 xh[8];
        const float* xf = (const float*)xc;
        #pragma unroll
        for (int j = 0; j < 8; ++j) {
            h2 p; p.x = (_Float16)xf[2 * j]; p.y = (_Float16)xf[2 * j + 1];
            xh[j] = p;
        }
        {
            const int tn = (tt + 1 < TLEN) ? tt + 1 : TLEN - 1;
            const f4* xp = (const f4*)(X + ((size_t)b * TLEN + tn) * DIN + kg * 16);
            #pragma unroll
            for (int j = 0; j < 4; ++j) xn[j] = xp[j];
        }
        float p0[4];
        #pragma unroll
        for (int m = 0; m < 4; ++m) p0[m] = bi0[m];
        #pragma unroll
        for (int m = 0; m < 4; ++m) {
            const unsigned int* wr = &wih0_lds[(rg + 128 * m) * 33 + kg * 8];
            #pragma unroll
            for (int i = 0; i < 8; ++i) {
                h2 w = __builtin_bit_cast(h2, wr[i]);
                p0[m] = FDOT2(w, xh[i], p0[m]);
            }
        }
        {
            const unsigned int* hr = (const unsigned int*)&h0buf[cur][0];
            #pragma unroll
            for (int i = 0; i < 16; ++i) {
                h2 hv = __builtin_bit_cast(h2, hr[kg * 16 + i]);
                #pragma unroll
                for (int m = 0; m < 4; ++m)
                    p0[m] = FDOT2(whh0[m][i], hv, p0[m]);
            }
        }
        #pragma unroll
        for (int m = 0; m < 4; ++m) {
            p0[m] += __shfl_xor(p0[m], 1, 4);
            p0[m] += __shfl_xor(p0[m], 2, 4);
        }
        {
            float ii = sigm(p0[0]), ff = sigm(p0[1]);
            float gg = tanh_c(p0[2]), oo = sigm(p0[3]);
            c0 = ff * c0 + ii * gg;
            float h0v = oo * tanh_c(c0);
            if (kg == 0) h0buf[nxt][rg] = (_Float16)h0v;
        }
        __syncthreads();
        float q[4];
        #pragma unroll
        for (int m = 0; m < 4; ++m) q[m] = bi1[m];
        {
            const unsigned int* hr = (const unsigned int*)&h0buf[nxt][0];
            #pragma unroll
            for (int i = 0; i < 16; ++i) {
                h2 hv = __builtin_bit_cast(h2, hr[kg * 16 + i]);
                #pragma unroll
                for (int m = 0; m < 4; ++m)
                    q[m] = FDOT2(wih1[m][i], hv, q[m]);
            }
        }
        {
            const unsigned int* hr = (const unsigned int*)&h1buf[cur][0];
            #pragma unroll
            for (int i = 0; i < 16; ++i) {
                h2 hv = __builtin_bit_cast(h2, hr[kg * 16 + i]);
                #pragma unroll
                for (int m = 0; m < 4; ++m)
                    q[m] = FDOT2(whh1[m][i], hv, q[m]);
            }
        }
        #pragma unroll
        for (int m = 0; m < 4; ++m) {
            q[m] += __shfl_xor(q[m], 1, 4);
            q[m] += __shfl_xor(q[m], 2, 4);
        }
        {
            float ii = sigm(q[0]), ff = sigm(q[1]);
            float gg = tanh_c(q[2]), oo = sigm(q[3]);
            c1 = ff * c1 + ii * gg;
            float h1v = oo * tanh_c(c1);
            if (kg == 0) {
                h1buf[nxt][rg] = (_Float16)h1v;
                Out[((size_t)b * TLEN + tt) * HID + rg] = h1v;
            }
        }
        __syncthreads();
    };

    for (int tt = 0; tt < TLEN; tt += 2) {
        step(tt, xA, xB);
        step(tt + 1, xB, xA);
    }
}

extern "C" void kernel_launch(void* const* d_in, const int* in_sizes, int n_in,
                              void* d_out, int out_size, void* d_ws, size_t ws_size,
                              hipStream_t stream) {
    const float* X    = (const float*)d_in[0];
    const float* Wih0 = (const float*)d_in[1];
    const float* Whh0 = (const float*)d_in[2];
    const float* bih0 = (const float*)d_in[3];
    const float* bhh0 = (const float*)d_in[4];
    const float* Wih1 = (const float*)d_in[5];
    const float* Whh1 = (const float*)d_in[6];
    const float* bih1 = (const float*)d_in[7];
    const float* bhh1 = (const float*)d_in[8];
    float* Out = (float*)d_out;

    const size_t NG = (size_t)BATCH * TLEN * 512;        // xg element count
    if (ws_size >= NG * sizeof(float)) {
        float* XG = (float*)d_ws;
        xg_precompute<float><<<dim3(BATCH * (TLEN / 16)), dim3(512), 0, stream>>>(
            X, Wih0, bih0, bhh0, XG);
        lstm2_fused<float><<<dim3(BATCH), dim3(512), 0, stream>>>(
            XG, Whh0, Wih1, Whh1, bih1, bhh1, Out);
    } else if (ws_size >= NG * sizeof(_Float16)) {
        _Float16* XG = (_Float16*)d_ws;
        xg_precompute<_Float16><<<dim3(BATCH * (TLEN / 16)), dim3(512), 0, stream>>>(
            X, Wih0, bih0, bhh0, XG);
        lstm2_fused<_Float16><<<dim3(BATCH), dim3(512), 0, stream>>>(
            XG, Whh0, Wih1, Whh1, bih1, bhh1, Out);
    } else {
        lstm2_persist<<<dim3(BATCH), dim3(512), 0, stream>>>(
            X, Wih0, Whh0, bih0, bhh0, Wih1, Whh1, bih1, bhh1, Out);
    }
}